// Round 3
// baseline (422.745 us; speedup 1.0000x reference)
//
#include <hip/hip_runtime.h>

#define F 128
#define H 64
#define O 16

#define BSHIFT 7
#define BSZ 128       // nodes per coarse bucket
#define NSUB 16       // privatized cursor sub-regions per bucket
#define SUBCAP 384    // capacity per (bucket,sub): mean 256, +8 sigma
#define ACHUNK 8192   // edges per bucketA block
#define XS 136        // gemm1 LDS row stride in f16

typedef _Float16 half8_t __attribute__((ext_vector_type(8)));
typedef _Float16 half4_t __attribute__((ext_vector_type(4)));
typedef float f32x4 __attribute__((ext_vector_type(4)));

// fp16->fp32 accumulate without separate cvt: one v_fma_mix_f32 per feature.
// Numerically exact (f16 promotes losslessly inside the mix-fma).
#define MIX2(alo, ahi, dw)                                                              \
    do {                                                                                \
        asm("v_fma_mix_f32 %0, %1, 1.0, %0 op_sel_hi:[1,0,0]"                           \
            : "+v"(alo) : "v"(dw));                                                     \
        asm("v_fma_mix_f32 %0, %1, 1.0, %0 op_sel:[1,0,0] op_sel_hi:[1,0,0]"            \
            : "+v"(ahi) : "v"(dw));                                                     \
    } while (0)

#define MIXROW(r)                                                                       \
    do {                                                                                \
        MIX2(acc[0], acc[1], (r).x);                                                    \
        MIX2(acc[2], acc[3], (r).y);                                                    \
        MIX2(acc[4], acc[5], (r).z);                                                    \
        MIX2(acc[6], acc[7], (r).w);                                                    \
    } while (0)

// ---------- prep: W1 hi/lo transpose split + cursor init + deg zero (merged) ----------
__global__ void k_prep(const float* __restrict__ W1, _Float16* __restrict__ wt_hi,
                       _Float16* __restrict__ wt_lo, int* __restrict__ bcur, int NC,
                       int* __restrict__ deg, int N) {
    int i = blockIdx.x * blockDim.x + threadIdx.x;
    if (i < NC) bcur[i] = i * SUBCAP;
    if (i < N) deg[i] = 0;
    if (i < H * F) {
        int c = i >> 7, k = i & 127;
        float w = W1[k * H + c];
        _Float16 hi = (_Float16)w;
        wt_hi[i] = hi;
        wt_lo[i] = (_Float16)(w - (float)hi);
    }
}

// ---------- bucket build: LDS-aggregated multisplit, privatized reservation ----------
// pass-2 operands held in registers; per-node degree counted here via L2-resident
// global atomics (frees k_bplace from its histogram sweep of bdata).
__global__ __launch_bounds__(512) void k_bucketA(const int* __restrict__ src,
                                                 const int* __restrict__ dstv,
                                                 int* __restrict__ bcur,
                                                 int* __restrict__ bdata,
                                                 int* __restrict__ deg, int E) {
    __shared__ int hist[1024];
    for (int t = threadIdx.x; t < 1024; t += 512) hist[t] = 0;
    __syncthreads();
    int base = blockIdx.x * ACHUNK;
    int end = min(base + ACHUNK, E);
    int tid = threadIdx.x;
    int4 s4r[4], d4r[4];
    bool ok[4];
    // pass 1: histogram (int4 reads, values retained in VGPRs) + global degree count
#pragma unroll
    for (int k = 0; k < 4; k++) {
        int i = base + tid * 4 + k * 2048;
        ok[k] = (i + 3 < end);
        if (ok[k]) {
            d4r[k] = *(const int4*)(dstv + i);
            s4r[k] = *(const int4*)(src + i);
            atomicAdd(&hist[d4r[k].x >> BSHIFT], 1);
            atomicAdd(&hist[d4r[k].y >> BSHIFT], 1);
            atomicAdd(&hist[d4r[k].z >> BSHIFT], 1);
            atomicAdd(&hist[d4r[k].w >> BSHIFT], 1);
            atomicAdd(&deg[d4r[k].x], 1);
            atomicAdd(&deg[d4r[k].y], 1);
            atomicAdd(&deg[d4r[k].z], 1);
            atomicAdd(&deg[d4r[k].w], 1);
        }
    }
    for (int i = base + ((end - base) & ~3) + tid; i < end; i += 512) {
        int d = dstv[i];
        atomicAdd(&hist[d >> BSHIFT], 1);
        atomicAdd(&deg[d], 1);
    }
    __syncthreads();
    // reserve ranges in this block's private sub-region cursors
    int sub = blockIdx.x & (NSUB - 1);
    for (int b = tid; b < 1024; b += 512) {
        int c = hist[b];
        if (c > 0) hist[b] = atomicAdd(&bcur[b * NSUB + sub], c);
    }
    __syncthreads();
    // pass 2: place packed (src<<7 | local_dst) from registers via LDS cursors
#pragma unroll
    for (int k = 0; k < 4; k++) {
        if (ok[k]) {
            int4 s4 = s4r[k];
            int4 d4 = d4r[k];
            int p0 = atomicAdd(&hist[d4.x >> BSHIFT], 1);
            bdata[p0] = (s4.x << BSHIFT) | (d4.x & (BSZ - 1));
            int p1 = atomicAdd(&hist[d4.y >> BSHIFT], 1);
            bdata[p1] = (s4.y << BSHIFT) | (d4.y & (BSZ - 1));
            int p2 = atomicAdd(&hist[d4.z >> BSHIFT], 1);
            bdata[p2] = (s4.z << BSHIFT) | (d4.z & (BSZ - 1));
            int p3 = atomicAdd(&hist[d4.w >> BSHIFT], 1);
            bdata[p3] = (s4.w << BSHIFT) | (d4.w & (BSZ - 1));
        }
    }
    for (int i = base + ((end - base) & ~3) + tid; i < end; i += 512) {
        int d = dstv[i];
        int pos = atomicAdd(&hist[d >> BSHIFT], 1);
        bdata[pos] = (src[i] << BSHIFT) | (d & (BSZ - 1));
    }
}

// 1-block scan over bucket totals (from bcur deltas)
__global__ void k_bscan(const int* __restrict__ bcur, int* __restrict__ bstart, int NBK) {
    __shared__ int s[1024];
    int tid = threadIdx.x;
    int tot = 0;
    if (tid < NBK) {
        for (int ss = 0; ss < NSUB; ss++)
            tot += bcur[tid * NSUB + ss] - (tid * NSUB + ss) * SUBCAP;
    }
    s[tid] = tot;
    __syncthreads();
    for (int off = 1; off < 1024; off <<= 1) {
        int v = (tid >= off) ? s[tid - off] : 0;
        __syncthreads();
        s[tid] += v;
        __syncthreads();
    }
    bstart[tid] = s[tid] - tot;  // exclusive
}

// per-bucket: deg load + local scan -> row_ptr + dis + exact CSR placement
// (histogram sweep removed: deg comes precomputed from k_bucketA)
__global__ __launch_bounds__(256) void k_bplace(const int* __restrict__ bdata,
                                                const int* __restrict__ bcur,
                                                const int* __restrict__ bstart,
                                                const int* __restrict__ deg,
                                                int* __restrict__ row_ptr,
                                                float* __restrict__ dis,
                                                int* __restrict__ col, int N) {
    __shared__ int pref[BSZ];
    __shared__ int cur[BSZ];
    int b = blockIdx.x;
    int node0 = b << BSHIFT;
    int nloc = min(BSZ, N - node0);
    int tid = threadIdx.x;
    int myDeg = 0;
    if (tid < nloc) myDeg = deg[node0 + tid];
    if (tid < BSZ) pref[tid] = myDeg;
    __syncthreads();
    // Hillis-Steele inclusive scan over 128
    for (int off = 1; off < BSZ; off <<= 1) {
        int v = (tid < BSZ && tid >= off) ? pref[tid - off] : 0;
        __syncthreads();
        if (tid < BSZ) pref[tid] += v;
        __syncthreads();
    }
    int base = bstart[b];
    if (tid < nloc) {
        int excl = base + pref[tid] - myDeg;
        cur[tid] = excl;
        row_ptr[node0 + tid] = excl;
        dis[node0 + tid] = rsqrtf((float)myDeg + 1.0f);
    }
    if (tid == 0) row_ptr[node0 + nloc] = base + pref[BSZ - 1];
    __syncthreads();
    // placement (stores confined to bucket's L2-hot window)
    for (int s = 0; s < NSUB; s++) {
        int start = (b * NSUB + s) * SUBCAP;
        int end = bcur[b * NSUB + s];
        for (int p = start + tid; p < end; p += 256) {
            int v = bdata[p];
            int pos = atomicAdd(&cur[v & (BSZ - 1)], 1);
            col[pos] = v >> BSHIFT;
        }
    }
}

// ---------- layer 1: h1p = fp16( (x @ W1) * dis[row] ), MFMA hi/lo split ----------
__global__ __launch_bounds__(256) void k_gemm1(const float* __restrict__ x,
                                               const _Float16* __restrict__ wt_hi,
                                               const _Float16* __restrict__ wt_lo,
                                               const float* __restrict__ dis,
                                               _Float16* __restrict__ h1p, int N) {
    __shared__ _Float16 xh[64 * XS], xl[64 * XS], wh[64 * XS], wl[64 * XS];
    int tid = threadIdx.x;
    int row0 = blockIdx.x * 64;
#pragma unroll
    for (int i = 0; i < 8; i++) {
        int idx = i * 256 + tid;          // 2048 float4
        int r = idx >> 5;
        int c = (idx & 31) * 4;
        int rr = row0 + r; if (rr >= N) rr = N - 1;
        float4 v = *(const float4*)(x + (size_t)rr * F + c);
        half4_t h = {(_Float16)v.x, (_Float16)v.y, (_Float16)v.z, (_Float16)v.w};
        half4_t l = {(_Float16)(v.x - (float)h[0]), (_Float16)(v.y - (float)h[1]),
                     (_Float16)(v.z - (float)h[2]), (_Float16)(v.w - (float)h[3])};
        *(half4_t*)(xh + r * XS + c) = h;
        *(half4_t*)(xl + r * XS + c) = l;
    }
#pragma unroll
    for (int i = 0; i < 4; i++) {
        int idx = i * 256 + tid;          // 1024
        int c = idx >> 4;
        int k8 = (idx & 15) * 8;
        *(half8_t*)(wh + c * XS + k8) = *(const half8_t*)(wt_hi + c * 128 + k8);
        *(half8_t*)(wl + c * XS + k8) = *(const half8_t*)(wt_lo + c * 128 + k8);
    }
    __syncthreads();
    int wv = tid >> 6, lane = tid & 63;
    int m = lane & 15, qd = lane >> 4;
    const _Float16* xhp = xh + (wv * 16 + m) * XS;
    const _Float16* xlp = xl + (wv * 16 + m) * XS;
    f32x4 acc[4] = {f32x4{0,0,0,0}, f32x4{0,0,0,0}, f32x4{0,0,0,0}, f32x4{0,0,0,0}};
#pragma unroll
    for (int kc = 0; kc < 4; kc++) {
        int ko = kc * 32 + qd * 8;
        half8_t ah = *(const half8_t*)(xhp + ko);
        half8_t al = *(const half8_t*)(xlp + ko);
#pragma unroll
        for (int nt = 0; nt < 4; nt++) {
            half8_t bh = *(const half8_t*)(wh + (nt * 16 + m) * XS + ko);
            half8_t bl = *(const half8_t*)(wl + (nt * 16 + m) * XS + ko);
            acc[nt] = __builtin_amdgcn_mfma_f32_16x16x32_f16(ah, bh, acc[nt], 0, 0, 0);
            acc[nt] = __builtin_amdgcn_mfma_f32_16x16x32_f16(ah, bl, acc[nt], 0, 0, 0);
            acc[nt] = __builtin_amdgcn_mfma_f32_16x16x32_f16(al, bh, acc[nt], 0, 0, 0);
        }
    }
#pragma unroll
    for (int reg = 0; reg < 4; reg++) {
        int row = row0 + wv * 16 + qd * 4 + reg;
        if (row < N) {
            float d = dis[row];
#pragma unroll
            for (int nt = 0; nt < 4; nt++) {
                h1p[(size_t)row * H + nt * 16 + m] = (_Float16)(acc[nt][reg] * d);
            }
        }
    }
}

// ---------- layer 1 aggregation + fused layer-2 transform ----------
// 32-bit byte-offset gathers (saddr form, 1 VALU/addr); W2 rows hoisted to regs.
__global__ __launch_bounds__(256) void k_gather1(const _Float16* __restrict__ h1p,
                                                 const float* __restrict__ dis,
                                                 const int* __restrict__ row_ptr,
                                                 const int* __restrict__ col,
                                                 const float* __restrict__ b1,
                                                 const float* __restrict__ W2,
                                                 _Float16* __restrict__ h2p, int N) {
    __shared__ float w2t[16 * 65];  // W2^T, stride 65 (2-way bank alias: free)
    int tid = threadIdx.x;
    {
        int idx = tid * 4;  // 256 threads x 4 = 1024 = 64*16
        float4 v = *(const float4*)(W2 + idx);
        const float* vp = (const float*)&v;
#pragma unroll
        for (int i = 0; i < 4; i++) {
            int e = idx + i;
            w2t[(e & 15) * 65 + (e >> 4)] = vp[i];
        }
    }
    __syncthreads();
    int lane = tid & 63;
    int g = lane >> 3;   // edge group / output col 0..7
    int t = lane & 7;    // 8-feature slot
    unsigned t16 = (unsigned)t * 16;     // byte offset of this lane's 16B chunk
    const char* hb = (const char*)h1p;
    float bb[8];
#pragma unroll
    for (int j = 0; j < 8; j++) bb[j] = b1[t * 8 + j];
    // hoist W2 rows into registers (loop-invariant; compiler wasn't hoisting LDS reads)
    float w1v[8], w2v[8];
#pragma unroll
    for (int j = 0; j < 8; j++) {
        w1v[j] = w2t[g * 65 + t * 8 + j];
        w2v[j] = w2t[(g + 8) * 65 + t * 8 + j];
    }

    for (int node = blockIdx.x * 4 + (tid >> 6); node < N; node += gridDim.x * 4) {
        float acc[8];
#pragma unroll
        for (int j = 0; j < 8; j++) acc[j] = 0.f;
        int e = row_ptr[node + 1];
        int p = row_ptr[node] + g;
        // 4 gathers in flight per group: covers the mean-degree-32 node in one round
        for (; p + 24 < e; p += 32) {
            int s0 = col[p], s1 = col[p + 8], s2 = col[p + 16], s3 = col[p + 24];
            int4 r0 = *(const int4*)(hb + (((unsigned)s0 << 7) + t16));
            int4 r1 = *(const int4*)(hb + (((unsigned)s1 << 7) + t16));
            int4 r2 = *(const int4*)(hb + (((unsigned)s2 << 7) + t16));
            int4 r3 = *(const int4*)(hb + (((unsigned)s3 << 7) + t16));
            MIXROW(r0); MIXROW(r1); MIXROW(r2); MIXROW(r3);
        }
        for (; p + 8 < e; p += 16) {
            int s0 = col[p], s1 = col[p + 8];
            int4 r0 = *(const int4*)(hb + (((unsigned)s0 << 7) + t16));
            int4 r1 = *(const int4*)(hb + (((unsigned)s1 << 7) + t16));
            MIXROW(r0); MIXROW(r1);
        }
        if (p < e) {
            int s0 = col[p];
            int4 r0 = *(const int4*)(hb + (((unsigned)s0 << 7) + t16));
            MIXROW(r0);
        }
        // self-loop row: add once (group 0 only), pre-reduce
        if (g == 0) {
            int4 rs = *(const int4*)(hb + (((unsigned)node << 7) + t16));
            MIXROW(rs);
        }
#pragma unroll
        for (int off = 8; off < 64; off <<= 1) {
#pragma unroll
            for (int j = 0; j < 8; j++) acc[j] += __shfl_xor(acc[j], off);
        }
        // all lanes now hold full sums (incl self) for features t*8+j
        float dn = dis[node];
        float o[8];
#pragma unroll
        for (int j = 0; j < 8; j++)
            o[j] = fmaxf(fmaf(acc[j], dn, bb[j]), 0.f);
        // fused gemm2: partial dots for c=g and c=g+8
        float p1 = 0.f, p2 = 0.f;
#pragma unroll
        for (int j = 0; j < 8; j++) {
            p1 = fmaf(o[j], w1v[j], p1);
            p2 = fmaf(o[j], w2v[j], p2);
        }
#pragma unroll
        for (int off = 1; off < 8; off <<= 1) {
            p1 += __shfl_xor(p1, off);
            p2 += __shfl_xor(p2, off);
        }
        if (t == 0) {
            h2p[(size_t)node * O + g]     = (_Float16)(p1 * dn);
            h2p[(size_t)node * O + g + 8] = (_Float16)(p2 * dn);
        }
    }
}

// ---------- layer 2 aggregation: 1 wave/node, 32 edges in flight, fp16 rows ----------
__global__ __launch_bounds__(256) void k_gather2(const _Float16* __restrict__ h2p,
                                                 const float* __restrict__ dis,
                                                 const int* __restrict__ row_ptr,
                                                 const int* __restrict__ col,
                                                 const float* __restrict__ b2,
                                                 float* __restrict__ z2, int N) {
    int tid = threadIdx.x;
    int lane = tid & 63;
    int g = lane >> 1;   // edge group 0..31
    int t = lane & 1;    // 16B slot
    unsigned t16 = (unsigned)t * 16;
    const char* hb = (const char*)h2p;
    float bb[8];
#pragma unroll
    for (int j = 0; j < 8; j++) bb[j] = b2[t * 8 + j];

    for (int node = blockIdx.x * 4 + (tid >> 6); node < N; node += gridDim.x * 4) {
        float acc[8];
#pragma unroll
        for (int j = 0; j < 8; j++) acc[j] = 0.f;
        int e = row_ptr[node + 1];
        for (int p = row_ptr[node] + g; p < e; p += 32) {
            int s = col[p];
            int4 r = *(const int4*)(hb + (((unsigned)s << 5) + t16));
            MIXROW(r);
        }
        if (g == 0) {
            int4 rs = *(const int4*)(hb + (((unsigned)node << 5) + t16));
            MIXROW(rs);
        }
#pragma unroll
        for (int off = 2; off < 64; off <<= 1) {
#pragma unroll
            for (int j = 0; j < 8; j++) acc[j] += __shfl_xor(acc[j], off);
        }
        if (g == 0) {
            float dn = dis[node];
            float o[8];
#pragma unroll
            for (int j = 0; j < 8; j++)
                o[j] = fmaf(acc[j], dn, bb[j]);
            float4* zp = (float4*)(z2 + (size_t)node * O + t * 8);
            zp[0] = float4{o[0], o[1], o[2], o[3]};
            zp[1] = float4{o[4], o[5], o[6], o[7]};
        }
    }
}

// ---------- link prediction logits: 4 lanes per pair ----------
__global__ __launch_bounds__(256) void k_logits(const float* __restrict__ z2,
                                                const int* __restrict__ pos,
                                                const int* __restrict__ neg,
                                                float* __restrict__ out, int P, int Q) {
    int tid = blockIdx.x * 256 + threadIdx.x;
    int i = tid >> 2;
    if (i >= P + Q) return;
    int k = tid & 3;
    unsigned k16 = (unsigned)k * 16;
    const char* zb = (const char*)z2;
    int a, b;
    if (i < P) { a = pos[i]; b = pos[P + i]; }
    else       { int t = i - P; a = neg[t]; b = neg[Q + t]; }
    float4 va = *(const float4*)(zb + (((unsigned)a << 6) + k16));
    float4 vb = *(const float4*)(zb + (((unsigned)b << 6) + k16));
    float r = va.x * vb.x + va.y * vb.y + va.z * vb.z + va.w * vb.w;
    r += __shfl_xor(r, 1);
    r += __shfl_xor(r, 2);
    if (k == 0) out[i] = r;
}

extern "C" void kernel_launch(void* const* d_in, const int* in_sizes, int n_in,
                              void* d_out, int out_size, void* d_ws, size_t ws_size,
                              hipStream_t stream) {
    const float* x   = (const float*)d_in[0];
    const int*   ei  = (const int*)d_in[1];
    const int*   pos = (const int*)d_in[2];
    const int*   neg = (const int*)d_in[3];
    const float* W1  = (const float*)d_in[4];
    const float* b1  = (const float*)d_in[5];
    const float* W2  = (const float*)d_in[6];
    const float* b2  = (const float*)d_in[7];
    float* out = (float*)d_out;

    int N = in_sizes[0] / F;
    int E = in_sizes[1] / 2;
    int P = in_sizes[2] / 2;
    int Q = in_sizes[3] / 2;
    const int* src  = ei;
    const int* dstv = ei + E;

    int Npad = ((N + 255) / 256) * 256;
    int Epad = (E + 63) & ~63;
    int NBK = (N + BSZ - 1) / BSZ;    // coarse buckets (782)
    int NC  = NBK * NSUB;             // privatized cursors (12512)

    // workspace layout (byte-exact; bdata aliases h1p — dead before k_gemm1 writes;
    // deg aliases z2 — deg dies at k_bplace, z2 born at k_gather2)
    char* w = (char*)d_ws;
    float*    dis     = (float*)w;    w += (size_t)Npad * 4;
    int*      row_ptr = (int*)w;      w += (size_t)(Npad + 256) * 4;
    int*      bcur    = (int*)w;      w += 16384 * 4;          // NC <= 16384
    int*      bstart  = (int*)w;      w += 1024 * 4;
    int*      col     = (int*)w;      w += (size_t)Epad * 4;
    _Float16* h1p     = (_Float16*)w;
    int*      bdata   = (int*)w;
    size_t h1b = (size_t)N * H * 2, bdb = (size_t)NC * SUBCAP * 4;
    w += (h1b > bdb ? h1b : bdb);
    _Float16* h2p     = (_Float16*)w; w += (size_t)N * O * 2;
    float*    z2      = (float*)w;    w += (size_t)N * O * 4;
    _Float16* wt_hi   = (_Float16*)w; w += (size_t)H * F * 2;  // 16KB
    _Float16* wt_lo   = (_Float16*)w;
    int*      deg     = (int*)z2;     // aliased (disjoint lifetime)

    int prepN = (NC > H * F) ? NC : H * F;
    if (N > prepN) prepN = N;

    // 8 launches total
    k_prep<<<(prepN + 255) / 256, 256, 0, stream>>>(W1, wt_hi, wt_lo, bcur, NC, deg, N);
    k_bucketA<<<(E + ACHUNK - 1) / ACHUNK, 512, 0, stream>>>(src, dstv, bcur, bdata, deg, E);
    k_bscan<<<1, 1024, 0, stream>>>(bcur, bstart, NBK);
    k_bplace<<<NBK, 256, 0, stream>>>(bdata, bcur, bstart, deg, row_ptr, dis, col, N);

    k_gemm1<<<(N + 63) / 64, 256, 0, stream>>>(x, wt_hi, wt_lo, dis, h1p, N);
    k_gather1<<<2048, 256, 0, stream>>>(h1p, dis, row_ptr, col, b1, W2, h2p, N);
    k_gather2<<<(N + 3) / 4, 256, 0, stream>>>(h2p, dis, row_ptr, col, b2, z2, N);
    k_logits<<<((P + Q) * 4 + 255) / 256, 256, 0, stream>>>(z2, pos, neg, out, P, Q);
}

// Round 4
// 310.112 us; speedup vs baseline: 1.3632x; 1.3632x over previous
//
#include <hip/hip_runtime.h>

#define F 128
#define H 64
#define O 16

#define BSHIFT 7
#define BSZ 128       // nodes per coarse bucket
#define NSUB 16       // privatized cursor sub-regions per bucket
#define SUBCAP 384    // capacity per (bucket,sub): mean 256, +8 sigma
#define ACHUNK 8192   // edges per bucketA block
#define XS 136        // gemm1 LDS row stride in f16

typedef _Float16 half8_t __attribute__((ext_vector_type(8)));
typedef _Float16 half4_t __attribute__((ext_vector_type(4)));
typedef float f32x4 __attribute__((ext_vector_type(4)));

// fp16->fp32 accumulate without separate cvt: one v_fma_mix_f32 per feature.
// Numerically exact (f16 promotes losslessly inside the mix-fma).
#define MIX2(alo, ahi, dw)                                                              \
    do {                                                                                \
        asm("v_fma_mix_f32 %0, %1, 1.0, %0 op_sel_hi:[1,0,0]"                           \
            : "+v"(alo) : "v"(dw));                                                     \
        asm("v_fma_mix_f32 %0, %1, 1.0, %0 op_sel:[1,0,0] op_sel_hi:[1,0,0]"            \
            : "+v"(ahi) : "v"(dw));                                                     \
    } while (0)

#define MIXROW(r)                                                                       \
    do {                                                                                \
        MIX2(acc[0], acc[1], (r).x);                                                    \
        MIX2(acc[2], acc[3], (r).y);                                                    \
        MIX2(acc[4], acc[5], (r).z);                                                    \
        MIX2(acc[6], acc[7], (r).w);                                                    \
    } while (0)

// ---------- prep: W1 hi/lo transpose split + cursor init (merged) ----------
__global__ void k_prep(const float* __restrict__ W1, _Float16* __restrict__ wt_hi,
                       _Float16* __restrict__ wt_lo, int* __restrict__ bcur, int NC) {
    int i = blockIdx.x * blockDim.x + threadIdx.x;
    if (i < NC) bcur[i] = i * SUBCAP;
    if (i < H * F) {
        int c = i >> 7, k = i & 127;
        float w = W1[k * H + c];
        _Float16 hi = (_Float16)w;
        wt_hi[i] = hi;
        wt_lo[i] = (_Float16)(w - (float)hi);
    }
}

// ---------- bucket build: LDS-aggregated multisplit, privatized reservation ----------
// pass-2 operands held in registers across the reservation step: edges are read
// from global exactly once. NO scattered global atomics (r3 lesson: 3.2M random
// device-scope atomics cost ~110us; bucket-local LDS atomics are ~50x cheaper).
__global__ __launch_bounds__(512) void k_bucketA(const int* __restrict__ src,
                                                 const int* __restrict__ dstv,
                                                 int* __restrict__ bcur,
                                                 int* __restrict__ bdata, int E) {
    __shared__ int hist[1024];
    for (int t = threadIdx.x; t < 1024; t += 512) hist[t] = 0;
    __syncthreads();
    int base = blockIdx.x * ACHUNK;
    int end = min(base + ACHUNK, E);
    int tid = threadIdx.x;
    int4 s4r[4], d4r[4];
    bool ok[4];
    // pass 1: histogram (int4 reads, values retained in VGPRs)
#pragma unroll
    for (int k = 0; k < 4; k++) {
        int i = base + tid * 4 + k * 2048;
        ok[k] = (i + 3 < end);
        if (ok[k]) {
            d4r[k] = *(const int4*)(dstv + i);
            s4r[k] = *(const int4*)(src + i);
            atomicAdd(&hist[d4r[k].x >> BSHIFT], 1);
            atomicAdd(&hist[d4r[k].y >> BSHIFT], 1);
            atomicAdd(&hist[d4r[k].z >> BSHIFT], 1);
            atomicAdd(&hist[d4r[k].w >> BSHIFT], 1);
        }
    }
    for (int i = base + ((end - base) & ~3) + tid; i < end; i += 512)
        atomicAdd(&hist[dstv[i] >> BSHIFT], 1);
    __syncthreads();
    // reserve ranges in this block's private sub-region cursors
    int sub = blockIdx.x & (NSUB - 1);
    for (int b = tid; b < 1024; b += 512) {
        int c = hist[b];
        if (c > 0) hist[b] = atomicAdd(&bcur[b * NSUB + sub], c);
    }
    __syncthreads();
    // pass 2: place packed (src<<7 | local_dst) from registers via LDS cursors
#pragma unroll
    for (int k = 0; k < 4; k++) {
        if (ok[k]) {
            int4 s4 = s4r[k];
            int4 d4 = d4r[k];
            int p0 = atomicAdd(&hist[d4.x >> BSHIFT], 1);
            bdata[p0] = (s4.x << BSHIFT) | (d4.x & (BSZ - 1));
            int p1 = atomicAdd(&hist[d4.y >> BSHIFT], 1);
            bdata[p1] = (s4.y << BSHIFT) | (d4.y & (BSZ - 1));
            int p2 = atomicAdd(&hist[d4.z >> BSHIFT], 1);
            bdata[p2] = (s4.z << BSHIFT) | (d4.z & (BSZ - 1));
            int p3 = atomicAdd(&hist[d4.w >> BSHIFT], 1);
            bdata[p3] = (s4.w << BSHIFT) | (d4.w & (BSZ - 1));
        }
    }
    for (int i = base + ((end - base) & ~3) + tid; i < end; i += 512) {
        int d = dstv[i];
        int pos = atomicAdd(&hist[d >> BSHIFT], 1);
        bdata[pos] = (src[i] << BSHIFT) | (d & (BSZ - 1));
    }
}

// 1-block scan over bucket totals (from bcur deltas)
__global__ void k_bscan(const int* __restrict__ bcur, int* __restrict__ bstart, int NBK) {
    __shared__ int s[1024];
    int tid = threadIdx.x;
    int tot = 0;
    if (tid < NBK) {
        for (int ss = 0; ss < NSUB; ss++)
            tot += bcur[tid * NSUB + ss] - (tid * NSUB + ss) * SUBCAP;
    }
    s[tid] = tot;
    __syncthreads();
    for (int off = 1; off < 1024; off <<= 1) {
        int v = (tid >= off) ? s[tid - off] : 0;
        __syncthreads();
        s[tid] += v;
        __syncthreads();
    }
    bstart[tid] = s[tid] - tot;  // exclusive
}

// per-bucket: histogram + local scan -> row_ptr + dis + exact CSR placement
__global__ __launch_bounds__(256) void k_bplace(const int* __restrict__ bdata,
                                                const int* __restrict__ bcur,
                                                const int* __restrict__ bstart,
                                                int* __restrict__ row_ptr,
                                                float* __restrict__ dis,
                                                int* __restrict__ col, int N) {
    __shared__ int h[BSZ];
    __shared__ int pref[BSZ];
    __shared__ int cur[BSZ];
    int b = blockIdx.x;
    int node0 = b << BSHIFT;
    int nloc = min(BSZ, N - node0);
    int tid = threadIdx.x;
    if (tid < BSZ) h[tid] = 0;
    __syncthreads();
    // pass 1: per-bucket degree histogram
    for (int s = 0; s < NSUB; s++) {
        int start = (b * NSUB + s) * SUBCAP;
        int end = bcur[b * NSUB + s];
        for (int p = start + tid; p < end; p += 256)
            atomicAdd(&h[bdata[p] & (BSZ - 1)], 1);
    }
    __syncthreads();
    int myDeg = 0;
    if (tid < BSZ) {
        myDeg = h[tid];
        pref[tid] = myDeg;
    }
    __syncthreads();
    // Hillis-Steele inclusive scan over 128
    for (int off = 1; off < BSZ; off <<= 1) {
        int v = (tid < BSZ && tid >= off) ? pref[tid - off] : 0;
        __syncthreads();
        if (tid < BSZ) pref[tid] += v;
        __syncthreads();
    }
    int base = bstart[b];
    if (tid < nloc) {
        int excl = base + pref[tid] - myDeg;
        cur[tid] = excl;
        row_ptr[node0 + tid] = excl;
        dis[node0 + tid] = rsqrtf((float)myDeg + 1.0f);
    }
    if (tid == 0) row_ptr[node0 + nloc] = base + pref[BSZ - 1];
    __syncthreads();
    // pass 2: exact placement (stores confined to bucket's L2-hot window)
    for (int s = 0; s < NSUB; s++) {
        int start = (b * NSUB + s) * SUBCAP;
        int end = bcur[b * NSUB + s];
        for (int p = start + tid; p < end; p += 256) {
            int v = bdata[p];
            int pos = atomicAdd(&cur[v & (BSZ - 1)], 1);
            col[pos] = v >> BSHIFT;
        }
    }
}

// ---------- layer 1: h1p = fp16( (x @ W1) * dis[row] ), MFMA hi/lo split ----------
__global__ __launch_bounds__(256) void k_gemm1(const float* __restrict__ x,
                                               const _Float16* __restrict__ wt_hi,
                                               const _Float16* __restrict__ wt_lo,
                                               const float* __restrict__ dis,
                                               _Float16* __restrict__ h1p, int N) {
    __shared__ _Float16 xh[64 * XS], xl[64 * XS], wh[64 * XS], wl[64 * XS];
    int tid = threadIdx.x;
    int row0 = blockIdx.x * 64;
#pragma unroll
    for (int i = 0; i < 8; i++) {
        int idx = i * 256 + tid;          // 2048 float4
        int r = idx >> 5;
        int c = (idx & 31) * 4;
        int rr = row0 + r; if (rr >= N) rr = N - 1;
        float4 v = *(const float4*)(x + (size_t)rr * F + c);
        half4_t h = {(_Float16)v.x, (_Float16)v.y, (_Float16)v.z, (_Float16)v.w};
        half4_t l = {(_Float16)(v.x - (float)h[0]), (_Float16)(v.y - (float)h[1]),
                     (_Float16)(v.z - (float)h[2]), (_Float16)(v.w - (float)h[3])};
        *(half4_t*)(xh + r * XS + c) = h;
        *(half4_t*)(xl + r * XS + c) = l;
    }
#pragma unroll
    for (int i = 0; i < 4; i++) {
        int idx = i * 256 + tid;          // 1024
        int c = idx >> 4;
        int k8 = (idx & 15) * 8;
        *(half8_t*)(wh + c * XS + k8) = *(const half8_t*)(wt_hi + c * 128 + k8);
        *(half8_t*)(wl + c * XS + k8) = *(const half8_t*)(wt_lo + c * 128 + k8);
    }
    __syncthreads();
    int wv = tid >> 6, lane = tid & 63;
    int m = lane & 15, qd = lane >> 4;
    const _Float16* xhp = xh + (wv * 16 + m) * XS;
    const _Float16* xlp = xl + (wv * 16 + m) * XS;
    f32x4 acc[4] = {f32x4{0,0,0,0}, f32x4{0,0,0,0}, f32x4{0,0,0,0}, f32x4{0,0,0,0}};
#pragma unroll
    for (int kc = 0; kc < 4; kc++) {
        int ko = kc * 32 + qd * 8;
        half8_t ah = *(const half8_t*)(xhp + ko);
        half8_t al = *(const half8_t*)(xlp + ko);
#pragma unroll
        for (int nt = 0; nt < 4; nt++) {
            half8_t bh = *(const half8_t*)(wh + (nt * 16 + m) * XS + ko);
            half8_t bl = *(const half8_t*)(wl + (nt * 16 + m) * XS + ko);
            acc[nt] = __builtin_amdgcn_mfma_f32_16x16x32_f16(ah, bh, acc[nt], 0, 0, 0);
            acc[nt] = __builtin_amdgcn_mfma_f32_16x16x32_f16(ah, bl, acc[nt], 0, 0, 0);
            acc[nt] = __builtin_amdgcn_mfma_f32_16x16x32_f16(al, bh, acc[nt], 0, 0, 0);
        }
    }
#pragma unroll
    for (int reg = 0; reg < 4; reg++) {
        int row = row0 + wv * 16 + qd * 4 + reg;
        if (row < N) {
            float d = dis[row];
#pragma unroll
            for (int nt = 0; nt < 4; nt++) {
                h1p[(size_t)row * H + nt * 16 + m] = (_Float16)(acc[nt][reg] * d);
            }
        }
    }
}

// ---------- layer 1 aggregation + fused layer-2 transform ----------
// 32-bit byte-offset gathers (saddr form, 1 VALU/addr); W2 rows hoisted to regs.
__global__ __launch_bounds__(256) void k_gather1(const _Float16* __restrict__ h1p,
                                                 const float* __restrict__ dis,
                                                 const int* __restrict__ row_ptr,
                                                 const int* __restrict__ col,
                                                 const float* __restrict__ b1,
                                                 const float* __restrict__ W2,
                                                 _Float16* __restrict__ h2p, int N) {
    __shared__ float w2t[16 * 65];  // W2^T, stride 65 (2-way bank alias: free)
    int tid = threadIdx.x;
    {
        int idx = tid * 4;  // 256 threads x 4 = 1024 = 64*16
        float4 v = *(const float4*)(W2 + idx);
        const float* vp = (const float*)&v;
#pragma unroll
        for (int i = 0; i < 4; i++) {
            int e = idx + i;
            w2t[(e & 15) * 65 + (e >> 4)] = vp[i];
        }
    }
    __syncthreads();
    int lane = tid & 63;
    int g = lane >> 3;   // edge group / output col 0..7
    int t = lane & 7;    // 8-feature slot
    unsigned t16 = (unsigned)t * 16;     // byte offset of this lane's 16B chunk
    const char* hb = (const char*)h1p;
    float bb[8];
#pragma unroll
    for (int j = 0; j < 8; j++) bb[j] = b1[t * 8 + j];
    // hoist W2 rows into registers (loop-invariant; compiler wasn't hoisting LDS reads)
    float w1v[8], w2v[8];
#pragma unroll
    for (int j = 0; j < 8; j++) {
        w1v[j] = w2t[g * 65 + t * 8 + j];
        w2v[j] = w2t[(g + 8) * 65 + t * 8 + j];
    }

    for (int node = blockIdx.x * 4 + (tid >> 6); node < N; node += gridDim.x * 4) {
        float acc[8];
#pragma unroll
        for (int j = 0; j < 8; j++) acc[j] = 0.f;
        int e = row_ptr[node + 1];
        int p = row_ptr[node] + g;
        // 4 gathers in flight per group: covers the mean-degree-32 node in one round
        for (; p + 24 < e; p += 32) {
            int s0 = col[p], s1 = col[p + 8], s2 = col[p + 16], s3 = col[p + 24];
            int4 r0 = *(const int4*)(hb + (((unsigned)s0 << 7) + t16));
            int4 r1 = *(const int4*)(hb + (((unsigned)s1 << 7) + t16));
            int4 r2 = *(const int4*)(hb + (((unsigned)s2 << 7) + t16));
            int4 r3 = *(const int4*)(hb + (((unsigned)s3 << 7) + t16));
            MIXROW(r0); MIXROW(r1); MIXROW(r2); MIXROW(r3);
        }
        for (; p + 8 < e; p += 16) {
            int s0 = col[p], s1 = col[p + 8];
            int4 r0 = *(const int4*)(hb + (((unsigned)s0 << 7) + t16));
            int4 r1 = *(const int4*)(hb + (((unsigned)s1 << 7) + t16));
            MIXROW(r0); MIXROW(r1);
        }
        if (p < e) {
            int s0 = col[p];
            int4 r0 = *(const int4*)(hb + (((unsigned)s0 << 7) + t16));
            MIXROW(r0);
        }
        // self-loop row: add once (group 0 only), pre-reduce
        if (g == 0) {
            int4 rs = *(const int4*)(hb + (((unsigned)node << 7) + t16));
            MIXROW(rs);
        }
#pragma unroll
        for (int off = 8; off < 64; off <<= 1) {
#pragma unroll
            for (int j = 0; j < 8; j++) acc[j] += __shfl_xor(acc[j], off);
        }
        // all lanes now hold full sums (incl self) for features t*8+j
        float dn = dis[node];
        float o[8];
#pragma unroll
        for (int j = 0; j < 8; j++)
            o[j] = fmaxf(fmaf(acc[j], dn, bb[j]), 0.f);
        // fused gemm2: partial dots for c=g and c=g+8
        float p1 = 0.f, p2 = 0.f;
#pragma unroll
        for (int j = 0; j < 8; j++) {
            p1 = fmaf(o[j], w1v[j], p1);
            p2 = fmaf(o[j], w2v[j], p2);
        }
#pragma unroll
        for (int off = 1; off < 8; off <<= 1) {
            p1 += __shfl_xor(p1, off);
            p2 += __shfl_xor(p2, off);
        }
        if (t == 0) {
            h2p[(size_t)node * O + g]     = (_Float16)(p1 * dn);
            h2p[(size_t)node * O + g + 8] = (_Float16)(p2 * dn);
        }
    }
}

// ---------- layer 2 aggregation: 1 wave/node, 32 edges in flight, fp16 rows ----------
__global__ __launch_bounds__(256) void k_gather2(const _Float16* __restrict__ h2p,
                                                 const float* __restrict__ dis,
                                                 const int* __restrict__ row_ptr,
                                                 const int* __restrict__ col,
                                                 const float* __restrict__ b2,
                                                 float* __restrict__ z2, int N) {
    int tid = threadIdx.x;
    int lane = tid & 63;
    int g = lane >> 1;   // edge group 0..31
    int t = lane & 1;    // 16B slot
    unsigned t16 = (unsigned)t * 16;
    const char* hb = (const char*)h2p;
    float bb[8];
#pragma unroll
    for (int j = 0; j < 8; j++) bb[j] = b2[t * 8 + j];

    for (int node = blockIdx.x * 4 + (tid >> 6); node < N; node += gridDim.x * 4) {
        float acc[8];
#pragma unroll
        for (int j = 0; j < 8; j++) acc[j] = 0.f;
        int e = row_ptr[node + 1];
        for (int p = row_ptr[node] + g; p < e; p += 32) {
            int s = col[p];
            int4 r = *(const int4*)(hb + (((unsigned)s << 5) + t16));
            MIXROW(r);
        }
        if (g == 0) {
            int4 rs = *(const int4*)(hb + (((unsigned)node << 5) + t16));
            MIXROW(rs);
        }
#pragma unroll
        for (int off = 2; off < 64; off <<= 1) {
#pragma unroll
            for (int j = 0; j < 8; j++) acc[j] += __shfl_xor(acc[j], off);
        }
        if (g == 0) {
            float dn = dis[node];
            float o[8];
#pragma unroll
            for (int j = 0; j < 8; j++)
                o[j] = fmaf(acc[j], dn, bb[j]);
            float4* zp = (float4*)(z2 + (size_t)node * O + t * 8);
            zp[0] = float4{o[0], o[1], o[2], o[3]};
            zp[1] = float4{o[4], o[5], o[6], o[7]};
        }
    }
}

// ---------- link prediction logits: 4 lanes per pair ----------
__global__ __launch_bounds__(256) void k_logits(const float* __restrict__ z2,
                                                const int* __restrict__ pos,
                                                const int* __restrict__ neg,
                                                float* __restrict__ out, int P, int Q) {
    int tid = blockIdx.x * 256 + threadIdx.x;
    int i = tid >> 2;
    if (i >= P + Q) return;
    int k = tid & 3;
    unsigned k16 = (unsigned)k * 16;
    const char* zb = (const char*)z2;
    int a, b;
    if (i < P) { a = pos[i]; b = pos[P + i]; }
    else       { int t = i - P; a = neg[t]; b = neg[Q + t]; }
    float4 va = *(const float4*)(zb + (((unsigned)a << 6) + k16));
    float4 vb = *(const float4*)(zb + (((unsigned)b << 6) + k16));
    float r = va.x * vb.x + va.y * vb.y + va.z * vb.z + va.w * vb.w;
    r += __shfl_xor(r, 1);
    r += __shfl_xor(r, 2);
    if (k == 0) out[i] = r;
}

extern "C" void kernel_launch(void* const* d_in, const int* in_sizes, int n_in,
                              void* d_out, int out_size, void* d_ws, size_t ws_size,
                              hipStream_t stream) {
    const float* x   = (const float*)d_in[0];
    const int*   ei  = (const int*)d_in[1];
    const int*   pos = (const int*)d_in[2];
    const int*   neg = (const int*)d_in[3];
    const float* W1  = (const float*)d_in[4];
    const float* b1  = (const float*)d_in[5];
    const float* W2  = (const float*)d_in[6];
    const float* b2  = (const float*)d_in[7];
    float* out = (float*)d_out;

    int N = in_sizes[0] / F;
    int E = in_sizes[1] / 2;
    int P = in_sizes[2] / 2;
    int Q = in_sizes[3] / 2;
    const int* src  = ei;
    const int* dstv = ei + E;

    int Npad = ((N + 255) / 256) * 256;
    int Epad = (E + 63) & ~63;
    int NBK = (N + BSZ - 1) / BSZ;    // coarse buckets (782)
    int NC  = NBK * NSUB;             // privatized cursors (12512)

    // workspace layout (byte-exact; bdata aliases h1p — dead before k_gemm1 writes)
    char* w = (char*)d_ws;
    float*    dis     = (float*)w;    w += (size_t)Npad * 4;
    int*      row_ptr = (int*)w;      w += (size_t)(Npad + 256) * 4;
    int*      bcur    = (int*)w;      w += 16384 * 4;          // NC <= 16384
    int*      bstart  = (int*)w;      w += 1024 * 4;
    int*      col     = (int*)w;      w += (size_t)Epad * 4;
    _Float16* h1p     = (_Float16*)w;
    int*      bdata   = (int*)w;
    size_t h1b = (size_t)N * H * 2, bdb = (size_t)NC * SUBCAP * 4;
    w += (h1b > bdb ? h1b : bdb);
    _Float16* h2p     = (_Float16*)w; w += (size_t)N * O * 2;
    float*    z2      = (float*)w;    w += (size_t)N * O * 4;
    _Float16* wt_hi   = (_Float16*)w; w += (size_t)H * F * 2;  // 16KB
    _Float16* wt_lo   = (_Float16*)w;

    int prepN = (NC > H * F) ? NC : H * F;

    // 8 launches total
    k_prep<<<(prepN + 255) / 256, 256, 0, stream>>>(W1, wt_hi, wt_lo, bcur, NC);
    k_bucketA<<<(E + ACHUNK - 1) / ACHUNK, 512, 0, stream>>>(src, dstv, bcur, bdata, E);
    k_bscan<<<1, 1024, 0, stream>>>(bcur, bstart, NBK);
    k_bplace<<<NBK, 256, 0, stream>>>(bdata, bcur, bstart, row_ptr, dis, col, N);

    k_gemm1<<<(N + 63) / 64, 256, 0, stream>>>(x, wt_hi, wt_lo, dis, h1p, N);
    k_gather1<<<2048, 256, 0, stream>>>(h1p, dis, row_ptr, col, b1, W2, h2p, N);
    k_gather2<<<(N + 3) / 4, 256, 0, stream>>>(h2p, dis, row_ptr, col, b2, z2, N);
    k_logits<<<((P + Q) * 4 + 255) / 256, 256, 0, stream>>>(z2, pos, neg, out, P, Q);
}

// Round 5
// 305.851 us; speedup vs baseline: 1.3822x; 1.0139x over previous
//
#include <hip/hip_runtime.h>

#define F 128
#define H 64
#define O 16

#define BSHIFT 7
#define BSZ 128       // nodes per coarse bucket
#define NSUB 16       // privatized cursor sub-regions per bucket
#define SUBCAP 384    // capacity per (bucket,sub): mean 256, +8 sigma
#define ACHUNK 8192   // edges per bucketA block
#define XS 136        // gemm1 LDS row stride in f16

typedef _Float16 half8_t __attribute__((ext_vector_type(8)));
typedef _Float16 half4_t __attribute__((ext_vector_type(4)));
typedef float f32x4 __attribute__((ext_vector_type(4)));

// fp16->fp32 accumulate without separate cvt: one v_fma_mix_f32 per feature.
// Numerically exact (f16 promotes losslessly inside the mix-fma).
#define MIX2(alo, ahi, dw)                                                              \
    do {                                                                                \
        asm("v_fma_mix_f32 %0, %1, 1.0, %0 op_sel_hi:[1,0,0]"                           \
            : "+v"(alo) : "v"(dw));                                                     \
        asm("v_fma_mix_f32 %0, %1, 1.0, %0 op_sel:[1,0,0] op_sel_hi:[1,0,0]"            \
            : "+v"(ahi) : "v"(dw));                                                     \
    } while (0)

#define MIXROW(r)                                                                       \
    do {                                                                                \
        MIX2(acc[0], acc[1], (r).x);                                                    \
        MIX2(acc[2], acc[3], (r).y);                                                    \
        MIX2(acc[4], acc[5], (r).z);                                                    \
        MIX2(acc[6], acc[7], (r).w);                                                    \
    } while (0)

// ---------- prep: W1 hi/lo transpose split + cursor init (merged) ----------
__global__ void k_prep(const float* __restrict__ W1, _Float16* __restrict__ wt_hi,
                       _Float16* __restrict__ wt_lo, int* __restrict__ bcur, int NC) {
    int i = blockIdx.x * blockDim.x + threadIdx.x;
    if (i < NC) bcur[i] = i * SUBCAP;
    if (i < H * F) {
        int c = i >> 7, k = i & 127;
        float w = W1[k * H + c];
        _Float16 hi = (_Float16)w;
        wt_hi[i] = hi;
        wt_lo[i] = (_Float16)(w - (float)hi);
    }
}

// ---------- bucket build: LDS-aggregated multisplit, privatized reservation ----------
// pass-2 operands held in registers across the reservation step: edges are read
// from global exactly once. NO scattered global atomics (r3 lesson: 3.2M random
// device-scope atomics cost ~110us; bucket-local LDS atomics are ~50x cheaper).
__global__ __launch_bounds__(512) void k_bucketA(const int* __restrict__ src,
                                                 const int* __restrict__ dstv,
                                                 int* __restrict__ bcur,
                                                 int* __restrict__ bdata, int E) {
    __shared__ int hist[1024];
    for (int t = threadIdx.x; t < 1024; t += 512) hist[t] = 0;
    __syncthreads();
    int base = blockIdx.x * ACHUNK;
    int end = min(base + ACHUNK, E);
    int tid = threadIdx.x;
    int4 s4r[4], d4r[4];
    bool ok[4];
    // pass 1: histogram (int4 reads, values retained in VGPRs)
#pragma unroll
    for (int k = 0; k < 4; k++) {
        int i = base + tid * 4 + k * 2048;
        ok[k] = (i + 3 < end);
        if (ok[k]) {
            d4r[k] = *(const int4*)(dstv + i);
            s4r[k] = *(const int4*)(src + i);
            atomicAdd(&hist[d4r[k].x >> BSHIFT], 1);
            atomicAdd(&hist[d4r[k].y >> BSHIFT], 1);
            atomicAdd(&hist[d4r[k].z >> BSHIFT], 1);
            atomicAdd(&hist[d4r[k].w >> BSHIFT], 1);
        }
    }
    for (int i = base + ((end - base) & ~3) + tid; i < end; i += 512)
        atomicAdd(&hist[dstv[i] >> BSHIFT], 1);
    __syncthreads();
    // reserve ranges in this block's private sub-region cursors
    int sub = blockIdx.x & (NSUB - 1);
    for (int b = tid; b < 1024; b += 512) {
        int c = hist[b];
        if (c > 0) hist[b] = atomicAdd(&bcur[b * NSUB + sub], c);
    }
    __syncthreads();
    // pass 2: place packed (src<<7 | local_dst) from registers via LDS cursors
#pragma unroll
    for (int k = 0; k < 4; k++) {
        if (ok[k]) {
            int4 s4 = s4r[k];
            int4 d4 = d4r[k];
            int p0 = atomicAdd(&hist[d4.x >> BSHIFT], 1);
            bdata[p0] = (s4.x << BSHIFT) | (d4.x & (BSZ - 1));
            int p1 = atomicAdd(&hist[d4.y >> BSHIFT], 1);
            bdata[p1] = (s4.y << BSHIFT) | (d4.y & (BSZ - 1));
            int p2 = atomicAdd(&hist[d4.z >> BSHIFT], 1);
            bdata[p2] = (s4.z << BSHIFT) | (d4.z & (BSZ - 1));
            int p3 = atomicAdd(&hist[d4.w >> BSHIFT], 1);
            bdata[p3] = (s4.w << BSHIFT) | (d4.w & (BSZ - 1));
        }
    }
    for (int i = base + ((end - base) & ~3) + tid; i < end; i += 512) {
        int d = dstv[i];
        int pos = atomicAdd(&hist[d >> BSHIFT], 1);
        bdata[pos] = (src[i] << BSHIFT) | (d & (BSZ - 1));
    }
}

// 1-block scan over bucket totals — wave-shfl scan, 1 barrier (was 20-barrier H-S)
__global__ void k_bscan(const int* __restrict__ bcur, int* __restrict__ bstart, int NBK) {
    __shared__ int wsum[16];
    int tid = threadIdx.x;           // 1024 threads = 16 waves
    int lane = tid & 63, wv = tid >> 6;
    int tot = 0;
    if (tid < NBK) {
        for (int ss = 0; ss < NSUB; ss++)
            tot += bcur[tid * NSUB + ss] - (tid * NSUB + ss) * SUBCAP;
    }
    int val = tot;
#pragma unroll
    for (int off = 1; off < 64; off <<= 1) {
        int u = __shfl_up(val, off);
        if (lane >= off) val += u;
    }
    if (lane == 63) wsum[wv] = val;
    __syncthreads();
    int add = 0;
    for (int j = 0; j < wv; j++) add += wsum[j];
    bstart[tid] = val + add - tot;  // exclusive
}

// per-bucket: histogram + local scan -> row_ptr + dis + exact CSR placement
__global__ __launch_bounds__(256) void k_bplace(const int* __restrict__ bdata,
                                                const int* __restrict__ bcur,
                                                const int* __restrict__ bstart,
                                                int* __restrict__ row_ptr,
                                                float* __restrict__ dis,
                                                int* __restrict__ col, int N) {
    __shared__ int h[BSZ];
    __shared__ int pref[BSZ];
    __shared__ int cur[BSZ];
    int b = blockIdx.x;
    int node0 = b << BSHIFT;
    int nloc = min(BSZ, N - node0);
    int tid = threadIdx.x;
    if (tid < BSZ) h[tid] = 0;
    __syncthreads();
    // pass 1: per-bucket degree histogram
    for (int s = 0; s < NSUB; s++) {
        int start = (b * NSUB + s) * SUBCAP;
        int end = bcur[b * NSUB + s];
        for (int p = start + tid; p < end; p += 256)
            atomicAdd(&h[bdata[p] & (BSZ - 1)], 1);
    }
    __syncthreads();
    int myDeg = 0;
    if (tid < BSZ) {
        myDeg = h[tid];
        pref[tid] = myDeg;
    }
    __syncthreads();
    // Hillis-Steele inclusive scan over 128
    for (int off = 1; off < BSZ; off <<= 1) {
        int v = (tid < BSZ && tid >= off) ? pref[tid - off] : 0;
        __syncthreads();
        if (tid < BSZ) pref[tid] += v;
        __syncthreads();
    }
    int base = bstart[b];
    if (tid < nloc) {
        int excl = base + pref[tid] - myDeg;
        cur[tid] = excl;
        row_ptr[node0 + tid] = excl;
        dis[node0 + tid] = rsqrtf((float)myDeg + 1.0f);
    }
    if (tid == 0) row_ptr[node0 + nloc] = base + pref[BSZ - 1];
    __syncthreads();
    // pass 2: exact placement (stores confined to bucket's L2-hot window)
    for (int s = 0; s < NSUB; s++) {
        int start = (b * NSUB + s) * SUBCAP;
        int end = bcur[b * NSUB + s];
        for (int p = start + tid; p < end; p += 256) {
            int v = bdata[p];
            int pos = atomicAdd(&cur[v & (BSZ - 1)], 1);
            col[pos] = v >> BSHIFT;
        }
    }
}

// ---------- layer 1: h1p = fp16( (x @ W1) * dis[row] ), MFMA hi/lo split ----------
__global__ __launch_bounds__(256) void k_gemm1(const float* __restrict__ x,
                                               const _Float16* __restrict__ wt_hi,
                                               const _Float16* __restrict__ wt_lo,
                                               const float* __restrict__ dis,
                                               _Float16* __restrict__ h1p, int N) {
    __shared__ _Float16 xh[64 * XS], xl[64 * XS], wh[64 * XS], wl[64 * XS];
    int tid = threadIdx.x;
    int row0 = blockIdx.x * 64;
#pragma unroll
    for (int i = 0; i < 8; i++) {
        int idx = i * 256 + tid;          // 2048 float4
        int r = idx >> 5;
        int c = (idx & 31) * 4;
        int rr = row0 + r; if (rr >= N) rr = N - 1;
        float4 v = *(const float4*)(x + (size_t)rr * F + c);
        half4_t h = {(_Float16)v.x, (_Float16)v.y, (_Float16)v.z, (_Float16)v.w};
        half4_t l = {(_Float16)(v.x - (float)h[0]), (_Float16)(v.y - (float)h[1]),
                     (_Float16)(v.z - (float)h[2]), (_Float16)(v.w - (float)h[3])};
        *(half4_t*)(xh + r * XS + c) = h;
        *(half4_t*)(xl + r * XS + c) = l;
    }
#pragma unroll
    for (int i = 0; i < 4; i++) {
        int idx = i * 256 + tid;          // 1024
        int c = idx >> 4;
        int k8 = (idx & 15) * 8;
        *(half8_t*)(wh + c * XS + k8) = *(const half8_t*)(wt_hi + c * 128 + k8);
        *(half8_t*)(wl + c * XS + k8) = *(const half8_t*)(wt_lo + c * 128 + k8);
    }
    __syncthreads();
    int wv = tid >> 6, lane = tid & 63;
    int m = lane & 15, qd = lane >> 4;
    const _Float16* xhp = xh + (wv * 16 + m) * XS;
    const _Float16* xlp = xl + (wv * 16 + m) * XS;
    f32x4 acc[4] = {f32x4{0,0,0,0}, f32x4{0,0,0,0}, f32x4{0,0,0,0}, f32x4{0,0,0,0}};
#pragma unroll
    for (int kc = 0; kc < 4; kc++) {
        int ko = kc * 32 + qd * 8;
        half8_t ah = *(const half8_t*)(xhp + ko);
        half8_t al = *(const half8_t*)(xlp + ko);
#pragma unroll
        for (int nt = 0; nt < 4; nt++) {
            half8_t bh = *(const half8_t*)(wh + (nt * 16 + m) * XS + ko);
            half8_t bl = *(const half8_t*)(wl + (nt * 16 + m) * XS + ko);
            acc[nt] = __builtin_amdgcn_mfma_f32_16x16x32_f16(ah, bh, acc[nt], 0, 0, 0);
            acc[nt] = __builtin_amdgcn_mfma_f32_16x16x32_f16(ah, bl, acc[nt], 0, 0, 0);
            acc[nt] = __builtin_amdgcn_mfma_f32_16x16x32_f16(al, bh, acc[nt], 0, 0, 0);
        }
    }
#pragma unroll
    for (int reg = 0; reg < 4; reg++) {
        int row = row0 + wv * 16 + qd * 4 + reg;
        if (row < N) {
            float d = dis[row];
#pragma unroll
            for (int nt = 0; nt < 4; nt++) {
                h1p[(size_t)row * H + nt * 16 + m] = (_Float16)(acc[nt][reg] * d);
            }
        }
    }
}

// ---------- layer 1 aggregation + fused layer-2 transform ----------
// 2 nodes per wave (32 lanes each): every epilogue instruction serves 2 nodes.
// Edge phase: 4 groups/node, stride 4, 4-deep. Reduce: xor 8,16 only.
// gemm2 keeps full-wave col mapping (g=lane>>3): halves exchange activations via
// shfl_xor(.,32); half0 computes cols 0-3/8-11 for BOTH nodes, half1 cols 4-7/12-15.
__global__ __launch_bounds__(256) void k_gather1(const _Float16* __restrict__ h1p,
                                                 const float* __restrict__ dis,
                                                 const int* __restrict__ row_ptr,
                                                 const int* __restrict__ col,
                                                 const float* __restrict__ b1,
                                                 const float* __restrict__ W2,
                                                 _Float16* __restrict__ h2p, int N) {
    __shared__ float w2t[16 * 65];  // W2^T, stride 65 (2-way bank alias: free)
    int tid = threadIdx.x;
    {
        int idx = tid * 4;  // 256 threads x 4 = 1024 = 64*16
        float4 v = *(const float4*)(W2 + idx);
        const float* vp = (const float*)&v;
#pragma unroll
        for (int i = 0; i < 4; i++) {
            int e = idx + i;
            w2t[(e & 15) * 65 + (e >> 4)] = vp[i];
        }
    }
    __syncthreads();
    int lane = tid & 63;
    int h = lane >> 5;          // which node of the wave's pair
    int g2 = (lane >> 3) & 3;   // edge group within half, 0..3
    int g = lane >> 3;          // full-wave output-col group, 0..7
    int t = lane & 7;           // 8-feature slot
    unsigned t16 = (unsigned)t * 16;
    const char* hb = (const char*)h1p;
    int hsign = 1 - 2 * h;      // other node = node + hsign
    float bb[8];
#pragma unroll
    for (int j = 0; j < 8; j++) bb[j] = b1[t * 8 + j];
    float w1v[8], w2v[8];
#pragma unroll
    for (int j = 0; j < 8; j++) {
        w1v[j] = w2t[g * 65 + t * 8 + j];
        w2v[j] = w2t[(g + 8) * 65 + t * 8 + j];
    }

    for (int node = blockIdx.x * 8 + (tid >> 6) * 2 + h; node < N; node += gridDim.x * 8) {
        float acc[8];
#pragma unroll
        for (int j = 0; j < 8; j++) acc[j] = 0.f;
        int e = row_ptr[node + 1];
        int p = row_ptr[node] + g2;
        // 4-deep pipeline, stride 4: a deg-32 node runs 2 full iterations
        for (; p + 12 < e; p += 16) {
            int s0 = col[p], s1 = col[p + 4], s2 = col[p + 8], s3 = col[p + 12];
            int4 r0 = *(const int4*)(hb + (((unsigned)s0 << 7) + t16));
            int4 r1 = *(const int4*)(hb + (((unsigned)s1 << 7) + t16));
            int4 r2 = *(const int4*)(hb + (((unsigned)s2 << 7) + t16));
            int4 r3 = *(const int4*)(hb + (((unsigned)s3 << 7) + t16));
            MIXROW(r0); MIXROW(r1); MIXROW(r2); MIXROW(r3);
        }
        for (; p + 4 < e; p += 8) {
            int s0 = col[p], s1 = col[p + 4];
            int4 r0 = *(const int4*)(hb + (((unsigned)s0 << 7) + t16));
            int4 r1 = *(const int4*)(hb + (((unsigned)s1 << 7) + t16));
            MIXROW(r0); MIXROW(r1);
        }
        if (p < e) {
            int s0 = col[p];
            int4 r0 = *(const int4*)(hb + (((unsigned)s0 << 7) + t16));
            MIXROW(r0);
        }
        // self-loop row: one group per half, pre-reduce
        if (g2 == 0) {
            int4 rs = *(const int4*)(hb + (((unsigned)node << 7) + t16));
            MIXROW(rs);
        }
        // reduce over the half's 4 groups (stays within the 32-lane half)
#pragma unroll
        for (int off = 8; off < 32; off <<= 1) {
#pragma unroll
            for (int j = 0; j < 8; j++) acc[j] += __shfl_xor(acc[j], off);
        }
        float dn = dis[node];
        float o[8];
#pragma unroll
        for (int j = 0; j < 8; j++)
            o[j] = fmaxf(fmaf(acc[j], dn, bb[j]), 0.f);
        // exchange activations across halves: oo = other node's o, dno = its dis
        float oo[8];
#pragma unroll
        for (int j = 0; j < 8; j++) oo[j] = __shfl_xor(o[j], 32);
        float dno = __shfl_xor(dn, 32);
        // fused gemm2: this lane's cols (g, g+8) for BOTH nodes
        float p1o = 0.f, p2o = 0.f, p1x = 0.f, p2x = 0.f;
#pragma unroll
        for (int j = 0; j < 8; j++) {
            p1o = fmaf(o[j], w1v[j], p1o);
            p2o = fmaf(o[j], w2v[j], p2o);
            p1x = fmaf(oo[j], w1v[j], p1x);
            p2x = fmaf(oo[j], w2v[j], p2x);
        }
#pragma unroll
        for (int off = 1; off < 8; off <<= 1) {
            p1o += __shfl_xor(p1o, off);
            p2o += __shfl_xor(p2o, off);
            p1x += __shfl_xor(p1x, off);
            p2x += __shfl_xor(p2x, off);
        }
        if (t == 0) {
            h2p[(size_t)node * O + g]     = (_Float16)(p1o * dn);
            h2p[(size_t)node * O + g + 8] = (_Float16)(p2o * dn);
            int nodeo = node + hsign;
            if (nodeo < N) {
                h2p[(size_t)nodeo * O + g]     = (_Float16)(p1x * dno);
                h2p[(size_t)nodeo * O + g + 8] = (_Float16)(p2x * dno);
            }
        }
    }
}

// ---------- layer 2 aggregation: 1 wave/node, 32 edges in flight, fp16 rows ----------
__global__ __launch_bounds__(256) void k_gather2(const _Float16* __restrict__ h2p,
                                                 const float* __restrict__ dis,
                                                 const int* __restrict__ row_ptr,
                                                 const int* __restrict__ col,
                                                 const float* __restrict__ b2,
                                                 float* __restrict__ z2, int N) {
    int tid = threadIdx.x;
    int lane = tid & 63;
    int g = lane >> 1;   // edge group 0..31
    int t = lane & 1;    // 16B slot
    unsigned t16 = (unsigned)t * 16;
    const char* hb = (const char*)h2p;
    float bb[8];
#pragma unroll
    for (int j = 0; j < 8; j++) bb[j] = b2[t * 8 + j];

    for (int node = blockIdx.x * 4 + (tid >> 6); node < N; node += gridDim.x * 4) {
        float acc[8];
#pragma unroll
        for (int j = 0; j < 8; j++) acc[j] = 0.f;
        int e = row_ptr[node + 1];
        for (int p = row_ptr[node] + g; p < e; p += 32) {
            int s = col[p];
            int4 r = *(const int4*)(hb + (((unsigned)s << 5) + t16));
            MIXROW(r);
        }
        if (g == 0) {
            int4 rs = *(const int4*)(hb + (((unsigned)node << 5) + t16));
            MIXROW(rs);
        }
#pragma unroll
        for (int off = 2; off < 64; off <<= 1) {
#pragma unroll
            for (int j = 0; j < 8; j++) acc[j] += __shfl_xor(acc[j], off);
        }
        if (g == 0) {
            float dn = dis[node];
            float o[8];
#pragma unroll
            for (int j = 0; j < 8; j++)
                o[j] = fmaf(acc[j], dn, bb[j]);
            float4* zp = (float4*)(z2 + (size_t)node * O + t * 8);
            zp[0] = float4{o[0], o[1], o[2], o[3]};
            zp[1] = float4{o[4], o[5], o[6], o[7]};
        }
    }
}

// ---------- link prediction logits: 4 lanes per pair ----------
__global__ __launch_bounds__(256) void k_logits(const float* __restrict__ z2,
                                                const int* __restrict__ pos,
                                                const int* __restrict__ neg,
                                                float* __restrict__ out, int P, int Q) {
    int tid = blockIdx.x * 256 + threadIdx.x;
    int i = tid >> 2;
    if (i >= P + Q) return;
    int k = tid & 3;
    unsigned k16 = (unsigned)k * 16;
    const char* zb = (const char*)z2;
    int a, b;
    if (i < P) { a = pos[i]; b = pos[P + i]; }
    else       { int t = i - P; a = neg[t]; b = neg[Q + t]; }
    float4 va = *(const float4*)(zb + (((unsigned)a << 6) + k16));
    float4 vb = *(const float4*)(zb + (((unsigned)b << 6) + k16));
    float r = va.x * vb.x + va.y * vb.y + va.z * vb.z + va.w * vb.w;
    r += __shfl_xor(r, 1);
    r += __shfl_xor(r, 2);
    if (k == 0) out[i] = r;
}

extern "C" void kernel_launch(void* const* d_in, const int* in_sizes, int n_in,
                              void* d_out, int out_size, void* d_ws, size_t ws_size,
                              hipStream_t stream) {
    const float* x   = (const float*)d_in[0];
    const int*   ei  = (const int*)d_in[1];
    const int*   pos = (const int*)d_in[2];
    const int*   neg = (const int*)d_in[3];
    const float* W1  = (const float*)d_in[4];
    const float* b1  = (const float*)d_in[5];
    const float* W2  = (const float*)d_in[6];
    const float* b2  = (const float*)d_in[7];
    float* out = (float*)d_out;

    int N = in_sizes[0] / F;
    int E = in_sizes[1] / 2;
    int P = in_sizes[2] / 2;
    int Q = in_sizes[3] / 2;
    const int* src  = ei;
    const int* dstv = ei + E;

    int Npad = ((N + 255) / 256) * 256;
    int Epad = (E + 63) & ~63;
    int NBK = (N + BSZ - 1) / BSZ;    // coarse buckets (782)
    int NC  = NBK * NSUB;             // privatized cursors (12512)

    // workspace layout (byte-exact; bdata aliases h1p — dead before k_gemm1 writes)
    char* w = (char*)d_ws;
    float*    dis     = (float*)w;    w += (size_t)Npad * 4;
    int*      row_ptr = (int*)w;      w += (size_t)(Npad + 256) * 4;
    int*      bcur    = (int*)w;      w += 16384 * 4;          // NC <= 16384
    int*      bstart  = (int*)w;      w += 1024 * 4;
    int*      col     = (int*)w;      w += (size_t)Epad * 4;
    _Float16* h1p     = (_Float16*)w;
    int*      bdata   = (int*)w;
    size_t h1b = (size_t)N * H * 2, bdb = (size_t)NC * SUBCAP * 4;
    w += (h1b > bdb ? h1b : bdb);
    _Float16* h2p     = (_Float16*)w; w += (size_t)N * O * 2;
    float*    z2      = (float*)w;    w += (size_t)N * O * 4;
    _Float16* wt_hi   = (_Float16*)w; w += (size_t)H * F * 2;  // 16KB
    _Float16* wt_lo   = (_Float16*)w;

    int prepN = (NC > H * F) ? NC : H * F;

    // 8 launches total
    k_prep<<<(prepN + 255) / 256, 256, 0, stream>>>(W1, wt_hi, wt_lo, bcur, NC);
    k_bucketA<<<(E + ACHUNK - 1) / ACHUNK, 512, 0, stream>>>(src, dstv, bcur, bdata, E);
    k_bscan<<<1, 1024, 0, stream>>>(bcur, bstart, NBK);
    k_bplace<<<NBK, 256, 0, stream>>>(bdata, bcur, bstart, row_ptr, dis, col, N);

    k_gemm1<<<(N + 63) / 64, 256, 0, stream>>>(x, wt_hi, wt_lo, dis, h1p, N);
    k_gather1<<<2048, 256, 0, stream>>>(h1p, dis, row_ptr, col, b1, W2, h2p, N);
    k_gather2<<<(N + 3) / 4, 256, 0, stream>>>(h2p, dis, row_ptr, col, b2, z2, N);
    k_logits<<<((P + Q) * 4 + 255) / 256, 256, 0, stream>>>(z2, pos, neg, out, P, Q);
}